// Round 11
// baseline (1568.367 us; speedup 1.0000x reference)
//
#include <hip/hip_runtime.h>
#include <hip/hip_bf16.h>

// Problem constants: B=4, N=2048, DIM=512, H=8, DH=64, ORDER=3, TOPK=64, INNER=512
#define SLOTS 80   // sparse slots per row (64 + tie headroom)

// ---------------------------------------------------------------------------
// K1/K4: fp32 tiled GEMM with bias: C = A(MxK) @ B(KxN) + bias(N)
// BM=BN=128, BK=16, 256 threads, 8x8 per thread. (unchanged)
// ---------------------------------------------------------------------------
__global__ __launch_bounds__(256)
void sgemm_bias(const float* __restrict__ A, const float* __restrict__ Bm,
                const float* __restrict__ bias, float* __restrict__ C,
                int M, int N, int K)
{
    __shared__ float As[16][132];
    __shared__ float Bs[16][132];

    const int t  = threadIdx.x;
    const int tx = t & 15, ty = t >> 4;
    const int bm = blockIdx.y << 7, bn = blockIdx.x << 7;

    const int arow = t >> 2,  ak4 = (t & 3) << 2;
    const int bkr  = t >> 5,  bc4 = (t & 31) << 2;

    float4 pa[2], pb[2];
#pragma unroll
    for (int s = 0; s < 2; ++s) {
        pa[s] = *(const float4*)&A[(size_t)(bm + arow + (s << 6)) * K + ak4];
        pb[s] = *(const float4*)&Bm[(size_t)(bkr + (s << 3)) * N + bn + bc4];
    }

    float acc[8][8] = {};

    for (int k0 = 0; k0 < K; k0 += 16) {
        __syncthreads();
#pragma unroll
        for (int s = 0; s < 2; ++s) {
            const int ar = arow + (s << 6);
            As[ak4 + 0][ar] = pa[s].x;
            As[ak4 + 1][ar] = pa[s].y;
            As[ak4 + 2][ar] = pa[s].z;
            As[ak4 + 3][ar] = pa[s].w;
            *(float4*)&Bs[bkr + (s << 3)][bc4] = pb[s];
        }
        __syncthreads();
        if (k0 + 16 < K) {
#pragma unroll
            for (int s = 0; s < 2; ++s) {
                pa[s] = *(const float4*)&A[(size_t)(bm + arow + (s << 6)) * K + k0 + 16 + ak4];
                pb[s] = *(const float4*)&Bm[(size_t)(k0 + 16 + bkr + (s << 3)) * N + bn + bc4];
            }
        }
#pragma unroll
        for (int kk = 0; kk < 16; ++kk) {
            float4 a0 = *(const float4*)&As[kk][(ty << 3) + 0];
            float4 a1 = *(const float4*)&As[kk][(ty << 3) + 4];
            float4 b0 = *(const float4*)&Bs[kk][(tx << 2)];
            float4 b1 = *(const float4*)&Bs[kk][64 + (tx << 2)];
            float ar[8] = {a0.x, a0.y, a0.z, a0.w, a1.x, a1.y, a1.z, a1.w};
            float br[8] = {b0.x, b0.y, b0.z, b0.w, b1.x, b1.y, b1.z, b1.w};
#pragma unroll
            for (int i = 0; i < 8; ++i)
#pragma unroll
                for (int j = 0; j < 8; ++j)
                    acc[i][j] = fmaf(ar[i], br[j], acc[i][j]);
        }
    }

    float bb[8];
#pragma unroll
    for (int j = 0; j < 4; ++j) {
        bb[j]     = bias[bn + (tx << 2) + j];
        bb[j + 4] = bias[bn + 64 + (tx << 2) + j];
    }
#pragma unroll
    for (int i = 0; i < 8; ++i) {
        const size_t row = (size_t)(bm + (ty << 3) + i);
        float4 o0 = {acc[i][0] + bb[0], acc[i][1] + bb[1], acc[i][2] + bb[2], acc[i][3] + bb[3]};
        float4 o1 = {acc[i][4] + bb[4], acc[i][5] + bb[5], acc[i][6] + bb[6], acc[i][7] + bb[7]};
        *(float4*)&C[row * N + bn + (tx << 2)]      = o0;
        *(float4*)&C[row * N + bn + 64 + (tx << 2)] = o1;
    }
}

// ---------------------------------------------------------------------------
// K2 v11: R10's clean structure at QUARTER block: 256 threads own 4 rows,
// S[4][2048] = 32 KB -> up to 5 blocks/CU (20 waves/CU, 5 waves/SIMD).
// Lane owns 8 cols (t + 256j), K chunks staged per COL-PAIR (8 float4 = 32
// regs) to stay under the 102-VGPR cap of launch_bounds(256,5).
// Phase B: 1 row/wave, bisection with EARLY EXIT when count==64 (kept set is
// then exactly the top-64 -> identical output; ties-only rows still run all
// 32 bits -> exact kth-value threshold as before).
// Per-score fmaf chain d-ascending 0..63, same S values in same slots ->
// bit-identical output to R8-R10.
// ---------------------------------------------------------------------------
__global__ __launch_bounds__(256, 5)
void scores_topk(const float* __restrict__ qkv, float* __restrict__ svals,
                 unsigned short* __restrict__ sidx, int* __restrict__ scnt)
{
    __shared__ float S[4][2048];   // 32 KiB

    const int t    = threadIdx.x;                   // 0..255
    const int lane = t & 63;
    const int wid  = t >> 6;                        // 0..3
    const int id   = blockIdx.x;                    // 0..16383
    const int bh   = ((id >> 12) << 3) | (id & 7);  // XCD-affine, bijective
    const int rowblk = (id >> 3) & 511;
    const int b = bh >> 3, h = bh & 7;
    const size_t rowbase = (size_t)b * 2048;
    const int r0 = rowblk << 2;                     // block's 4 rows

    // q base for the block's rows (uniform across lanes -> scalar loads)
    const float* qb = qkv + (rowbase + r0) * 1536 + (h << 6);
    // lane's 8 K-columns: t + 256j, j = 0..7
    const float* k0 = qkv + (rowbase + (size_t)t) * 1536 + 512 + (h << 6);

    float acc[4][8];
#pragma unroll
    for (int r = 0; r < 4; ++r)
#pragma unroll
        for (int j = 0; j < 8; ++j) acc[r][j] = 0.f;

    // Per sg (16 d): process cols in 4 pairs; each pair stages its two 64B
    // chunks (8 float4 = 32 regs) then runs 128 FMAs. All indices literal.
#pragma unroll 1
    for (int sg = 0; sg < 4; ++sg) {
#define COLPAIR(J0)                                                            \
    {                                                                          \
        float4 kva[4], kvb[4];                                                 \
        _Pragma("unroll")                                                      \
        for (int j = 0; j < 4; ++j) {                                          \
            kva[j] = *(const float4*)&k0[(size_t)(256 * (J0)) * 1536 +         \
                                         (sg << 4) + (j << 2)];                \
            kvb[j] = *(const float4*)&k0[(size_t)(256 * ((J0) + 1)) * 1536 +   \
                                         (sg << 4) + (j << 2)];                \
        }                                                                      \
        _Pragma("unroll")                                                      \
        for (int ss = 0; ss < 4; ++ss) {                                       \
            _Pragma("unroll")                                                  \
            for (int r = 0; r < 4; ++r) {                                      \
                const float4 q4 =                                              \
                    *(const float4*)&qb[r * 1536 + (sg << 4) + (ss << 2)];     \
                float a = acc[r][J0];                                          \
                a = fmaf(q4.x, kva[ss].x, a); a = fmaf(q4.y, kva[ss].y, a);    \
                a = fmaf(q4.z, kva[ss].z, a); a = fmaf(q4.w, kva[ss].w, a);    \
                acc[r][J0] = a;                                                \
                float c2 = acc[r][(J0) + 1];                                   \
                c2 = fmaf(q4.x, kvb[ss].x, c2); c2 = fmaf(q4.y, kvb[ss].y, c2);\
                c2 = fmaf(q4.z, kvb[ss].z, c2); c2 = fmaf(q4.w, kvb[ss].w, c2);\
                acc[r][(J0) + 1] = c2;                                         \
            }                                                                  \
        }                                                                      \
    }
        COLPAIR(0) COLPAIR(2) COLPAIR(4) COLPAIR(6)
#undef COLPAIR
    }

    // flush scaled scores to S (consecutive lanes -> consecutive addresses)
#pragma unroll
    for (int r = 0; r < 4; ++r)
#pragma unroll
        for (int j = 0; j < 8; ++j)
            S[r][t + (j << 8)] = acc[r][j] * 0.125f;
    __syncthreads();

    // phase B: ONE row per wave (rr = wid); exact 64th-largest via bisection
    const unsigned long long pre64 = (1ull << lane) - 1ull;
    {
        const int rr = wid;
        float    fv[32];
        unsigned uv[32];
#pragma unroll
        for (int m = 0; m < 32; ++m) {
            const float x = S[rr][lane + (m << 6)];
            fv[m] = x;
            const unsigned bx = __float_as_uint(x);
            uv[m] = bx ^ (unsigned)(((int)bx >> 31) | 0x80000000);
        }
        unsigned lo = 0;
#pragma unroll 1
        for (int bit = 31; bit >= 0; --bit) {
            const unsigned mid = lo | (1u << bit);
            int c = 0;
#pragma unroll
            for (int m = 0; m < 32; ++m)
                c += __popcll(__ballot(uv[m] >= mid));
            if (c >= 64) {
                lo = mid;              // uniform (ballot count is wave-uniform)
                if (c == 64) break;    // kept set is exactly the top-64
            }
        }
        unsigned um = 0;
#pragma unroll
        for (int m = 0; m < 32; ++m) um = uv[m] > um ? uv[m] : um;
#pragma unroll
        for (int off = 1; off < 64; off <<= 1) {
            const unsigned o = (unsigned)__shfl_xor((int)um, off, 64);
            um = o > um ? o : um;
        }
        const unsigned mbm = (um & 0x80000000u) ? (um ^ 0x80000000u) : ~um;
        const float Mx = __uint_as_float(mbm);

        float zs = 0.f;
#pragma unroll
        for (int m = 0; m < 32; ++m) {
            const bool keep = uv[m] >= lo;
            const float ex = keep ? __expf(fv[m] - Mx) : 0.f;
            fv[m] = ex;
            zs += ex;
        }
#pragma unroll
        for (int off = 1; off < 64; off <<= 1) zs += __shfl_xor(zs, off, 64);
        const float zinv = 1.0f / zs;

        const size_t grow = (size_t)bh * 2048 + r0 + rr;
        float* vd           = svals + grow * SLOTS;
        unsigned short* idp = sidx  + grow * SLOTS;
        int base = 0;
#pragma unroll
        for (int m = 0; m < 32; ++m) {
            const bool keep = uv[m] >= lo;
            unsigned long long ball = __ballot(keep);
            if (keep) {
                const int my = base + __popcll(ball & pre64);
                if (my < SLOTS) {
                    vd[my]  = fv[m] * zinv;
                    idp[my] = (unsigned short)(lane + (m << 6));
                }
            }
            base += __popcll(ball);
        }
        if (lane == 0) scnt[grow] = base < SLOTS ? base : SLOTS;
    }
}

// ---------------------------------------------------------------------------
// K3: sparse attn application. Gather loop unrolled x8 (same j order ->
// bit-identical) for more loads in flight.
// ---------------------------------------------------------------------------
__global__ __launch_bounds__(256)
void spmm(const float* __restrict__ svals, const unsigned short* __restrict__ sidx,
          const int* __restrict__ scnt, const float* __restrict__ qkv,
          const float* __restrict__ vin, float* __restrict__ vout,
          float* __restrict__ res, const float* __restrict__ alphas_raw, int order)
{
    const int lane = threadIdx.x & 63;
    const int gr   = (blockIdx.x << 2) + (threadIdx.x >> 6);  // 0..65535
    const int bh   = gr >> 11, n = gr & 2047;
    const int b    = bh >> 3,  h = bh & 7;

    const float* vb;
    int stride;
    if (order == 0) { vb = qkv + (size_t)b * 2048 * 1536 + 1024 + (h << 6); stride = 1536; }
    else            { vb = vin + ((size_t)bh << 17);                        stride = 64;   }

    const int cnt = scnt[gr];
    const float* va          = svals + (size_t)gr * SLOTS;
    const unsigned short* ia = sidx  + (size_t)gr * SLOTS;

    float acc = 0.f;
    int j = 0;
    for (; j + 8 <= cnt; j += 8) {
        float a0 = va[j],     a1 = va[j + 1], a2 = va[j + 2], a3 = va[j + 3];
        float a4 = va[j + 4], a5 = va[j + 5], a6 = va[j + 6], a7 = va[j + 7];
        int   i0 = ia[j],     i1 = ia[j + 1], i2 = ia[j + 2], i3 = ia[j + 3];
        int   i4 = ia[j + 4], i5 = ia[j + 5], i6 = ia[j + 6], i7 = ia[j + 7];
        acc += a0 * vb[(size_t)i0 * stride + lane];
        acc += a1 * vb[(size_t)i1 * stride + lane];
        acc += a2 * vb[(size_t)i2 * stride + lane];
        acc += a3 * vb[(size_t)i3 * stride + lane];
        acc += a4 * vb[(size_t)i4 * stride + lane];
        acc += a5 * vb[(size_t)i5 * stride + lane];
        acc += a6 * vb[(size_t)i6 * stride + lane];
        acc += a7 * vb[(size_t)i7 * stride + lane];
    }
    for (; j < cnt; ++j) acc += va[j] * vb[(size_t)ia[j] * stride + lane];

    if (order < 2) vout[((size_t)gr << 6) + lane] = acc;

    float ar    = alphas_raw[(order << 3) + h];
    float alpha = ar * 0.5f * (1.0f + erff(ar * 0.70710678f));  // exact gelu
    size_t ro = ((size_t)b * 2048 + n) * 512 + (h << 6) + lane;
    float av  = alpha * acc;
    if (order == 0) res[ro] = av;
    else            res[ro] += av;
}

// ---------------------------------------------------------------------------
extern "C" void kernel_launch(void* const* d_in, const int* in_sizes, int n_in,
                              void* d_out, int out_size, void* d_ws, size_t ws_size,
                              hipStream_t stream)
{
    const float* x      = (const float*)d_in[0];
    const float* Wqkv   = (const float*)d_in[1];
    const float* bqkv   = (const float*)d_in[2];
    const float* Wout   = (const float*)d_in[3];
    const float* bout   = (const float*)d_in[4];
    const float* alphas = (const float*)d_in[5];
    float* out = (float*)d_out;

    // workspace layout (bytes)
    char* ws = (char*)d_ws;
    float*          qkvb  = (float*)ws;                       // 8192*1536*4 = 50331648
    float*          svals = (float*)(ws + 50331648);          // 65536*80*4  = 20971520
    unsigned short* sidxp = (unsigned short*)(ws + 71303168); // 65536*80*2  = 10485760
    int*            scntp = (int*)(ws + 81788928);            // 65536*4     = 262144
    float*          v1    = (float*)(ws + 82051072);          // 16777216
    float*          v2    = (float*)(ws + 98828288);          // 16777216
    float*          resb  = (float*)(ws + 115605504);         // 16777216
    if (ws_size < 132382720) return;                          // need ~126 MB

    // K1: qkv = x @ Wqkv + bqkv
    sgemm_bias<<<dim3(1536 / 128, 8192 / 128), 256, 0, stream>>>(
        x, Wqkv, bqkv, qkvb, 8192, 1536, 512);

    // K2: scores -> exact top-64(+ties) -> softmax -> sparse rows
    // 16384 blocks x 256 threads; 4 rows/block; XCD-affine bh mapping
    scores_topk<<<16384, 256, 0, stream>>>(qkvb, svals, sidxp, scntp);

    // K3 x3: polynomial filter (sparse A applications)
    spmm<<<16384, 256, 0, stream>>>(svals, sidxp, scntp, qkvb, nullptr, v1, resb, alphas, 0);
    spmm<<<16384, 256, 0, stream>>>(svals, sidxp, scntp, qkvb, v1, v2, resb, alphas, 1);
    spmm<<<16384, 256, 0, stream>>>(svals, sidxp, scntp, qkvb, v2, nullptr, resb, alphas, 2);

    // K4: out = res @ Wout + bout
    sgemm_bias<<<dim3(512 / 128, 8192 / 128), 256, 0, stream>>>(
        resb, Wout, bout, out, 8192, 512, 512);
}

// Round 12
// 1294.587 us; speedup vs baseline: 1.2115x; 1.2115x over previous
//
#include <hip/hip_runtime.h>
#include <hip/hip_bf16.h>

// Problem constants: B=4, N=2048, DIM=512, H=8, DH=64, ORDER=3, TOPK=64, INNER=512
#define SLOTS 80   // sparse slots per row (64 + tie headroom)

// ---------------------------------------------------------------------------
// K1/K4: fp32 tiled GEMM with bias: C = A(MxK) @ B(KxN) + bias(N)
// BM=BN=128, BK=16, 256 threads, 8x8 per thread. (unchanged)
// ---------------------------------------------------------------------------
__global__ __launch_bounds__(256)
void sgemm_bias(const float* __restrict__ A, const float* __restrict__ Bm,
                const float* __restrict__ bias, float* __restrict__ C,
                int M, int N, int K)
{
    __shared__ float As[16][132];
    __shared__ float Bs[16][132];

    const int t  = threadIdx.x;
    const int tx = t & 15, ty = t >> 4;
    const int bm = blockIdx.y << 7, bn = blockIdx.x << 7;

    const int arow = t >> 2,  ak4 = (t & 3) << 2;
    const int bkr  = t >> 5,  bc4 = (t & 31) << 2;

    float4 pa[2], pb[2];
#pragma unroll
    for (int s = 0; s < 2; ++s) {
        pa[s] = *(const float4*)&A[(size_t)(bm + arow + (s << 6)) * K + ak4];
        pb[s] = *(const float4*)&Bm[(size_t)(bkr + (s << 3)) * N + bn + bc4];
    }

    float acc[8][8] = {};

    for (int k0 = 0; k0 < K; k0 += 16) {
        __syncthreads();
#pragma unroll
        for (int s = 0; s < 2; ++s) {
            const int ar = arow + (s << 6);
            As[ak4 + 0][ar] = pa[s].x;
            As[ak4 + 1][ar] = pa[s].y;
            As[ak4 + 2][ar] = pa[s].z;
            As[ak4 + 3][ar] = pa[s].w;
            *(float4*)&Bs[bkr + (s << 3)][bc4] = pb[s];
        }
        __syncthreads();
        if (k0 + 16 < K) {
#pragma unroll
            for (int s = 0; s < 2; ++s) {
                pa[s] = *(const float4*)&A[(size_t)(bm + arow + (s << 6)) * K + k0 + 16 + ak4];
                pb[s] = *(const float4*)&Bm[(size_t)(k0 + 16 + bkr + (s << 3)) * N + bn + bc4];
            }
        }
#pragma unroll
        for (int kk = 0; kk < 16; ++kk) {
            float4 a0 = *(const float4*)&As[kk][(ty << 3) + 0];
            float4 a1 = *(const float4*)&As[kk][(ty << 3) + 4];
            float4 b0 = *(const float4*)&Bs[kk][(tx << 2)];
            float4 b1 = *(const float4*)&Bs[kk][64 + (tx << 2)];
            float ar[8] = {a0.x, a0.y, a0.z, a0.w, a1.x, a1.y, a1.z, a1.w};
            float br[8] = {b0.x, b0.y, b0.z, b0.w, b1.x, b1.y, b1.z, b1.w};
#pragma unroll
            for (int i = 0; i < 8; ++i)
#pragma unroll
                for (int j = 0; j < 8; ++j)
                    acc[i][j] = fmaf(ar[i], br[j], acc[i][j]);
        }
    }

    float bb[8];
#pragma unroll
    for (int j = 0; j < 4; ++j) {
        bb[j]     = bias[bn + (tx << 2) + j];
        bb[j + 4] = bias[bn + 64 + (tx << 2) + j];
    }
#pragma unroll
    for (int i = 0; i < 8; ++i) {
        const size_t row = (size_t)(bm + (ty << 3) + i);
        float4 o0 = {acc[i][0] + bb[0], acc[i][1] + bb[1], acc[i][2] + bb[2], acc[i][3] + bb[3]};
        float4 o1 = {acc[i][4] + bb[4], acc[i][5] + bb[5], acc[i][6] + bb[6], acc[i][7] + bb[7]};
        *(float4*)&C[row * N + bn + (tx << 2)]      = o0;
        *(float4*)&C[row * N + bn + 64 + (tx << 2)] = o1;
    }
}

// ---------------------------------------------------------------------------
// K2 v12: EXACTLY R10's proven structure (512 thr / 8 rows / S[8][2048]=64KB
// / 2 blocks/CU / lane owns 4 cols / cache-line-linear K reads), plus:
//  (a) sched_barrier(0) after the 16 kv loads per sg: forbids the scheduler
//      from sinking loads into the FMA block -> all 16 in flight at once,
//      ONE latency exposure per sg (R10's VGPR=60 showed it was batching ~4).
//  (b) early-exit bisection: when count(>=mid)==64 the kept set is exactly
//      the top-64 -> threshold only used for membership -> identical output.
// Same fmaf chain (d-ascending), same S image, same compaction order ->
// bit-identical output (absmax 4.882812e-4).
// ---------------------------------------------------------------------------
__global__ __launch_bounds__(512, 4)
void scores_topk(const float* __restrict__ qkv, float* __restrict__ svals,
                 unsigned short* __restrict__ sidx, int* __restrict__ scnt)
{
    __shared__ float S[8][2048];   // 64 KiB

    const int t    = threadIdx.x;
    const int lane = t & 63;
    const int wid  = t >> 6;                        // 0..7
    const int id   = blockIdx.x;                    // 0..8191
    const int bh   = ((id >> 11) << 3) | (id & 7);  // XCD-affine, bijective
    const int rowblk = (id >> 3) & 255;
    const int b = bh >> 3, h = bh & 7;
    const size_t rowbase = (size_t)b * 2048;
    const int r0 = rowblk << 3;                     // block's 8 rows

    // q base for the block's rows (uniform across lanes -> scalar loads)
    const float* qb = qkv + (rowbase + r0) * 1536 + (h << 6);
    // lane's 4 K-columns: t + {0, 512, 1024, 1536}
    const float* k0 = qkv + (rowbase + (size_t)t) * 1536 + 512 + (h << 6);

    float acc[8][4];
#pragma unroll
    for (int r = 0; r < 8; ++r)
#pragma unroll
        for (int c = 0; c < 4; ++c) acc[r][c] = 0.f;

#pragma unroll 1
    for (int sg = 0; sg < 4; ++sg) {
        // load each column's full 64B chunk (4 consecutive float4: same line)
        float4 kv0[4], kv1[4], kv2[4], kv3[4];
#pragma unroll
        for (int j = 0; j < 4; ++j) {
            kv0[j] = *(const float4*)&k0[                   (sg << 4) + (j << 2)];
            kv1[j] = *(const float4*)&k0[ 512 * 1536 +      (sg << 4) + (j << 2)];
            kv2[j] = *(const float4*)&k0[1024 * 1536 +      (sg << 4) + (j << 2)];
            kv3[j] = *(const float4*)&k0[1536 * 1536 +      (sg << 4) + (j << 2)];
        }
        // issue ALL 16 loads before any FMA is scheduled (one latency exposure)
        __builtin_amdgcn_sched_barrier(0);
#pragma unroll
        for (int ss = 0; ss < 4; ++ss) {
#pragma unroll
            for (int r = 0; r < 8; ++r) {
                const float4 q4 = *(const float4*)&qb[r * 1536 + (sg << 4) + (ss << 2)];
                float a0 = acc[r][0], a1 = acc[r][1], a2 = acc[r][2], a3 = acc[r][3];
                a0 = fmaf(q4.x, kv0[ss].x, a0); a0 = fmaf(q4.y, kv0[ss].y, a0);
                a0 = fmaf(q4.z, kv0[ss].z, a0); a0 = fmaf(q4.w, kv0[ss].w, a0);
                a1 = fmaf(q4.x, kv1[ss].x, a1); a1 = fmaf(q4.y, kv1[ss].y, a1);
                a1 = fmaf(q4.z, kv1[ss].z, a1); a1 = fmaf(q4.w, kv1[ss].w, a1);
                a2 = fmaf(q4.x, kv2[ss].x, a2); a2 = fmaf(q4.y, kv2[ss].y, a2);
                a2 = fmaf(q4.z, kv2[ss].z, a2); a2 = fmaf(q4.w, kv2[ss].w, a2);
                a3 = fmaf(q4.x, kv3[ss].x, a3); a3 = fmaf(q4.y, kv3[ss].y, a3);
                a3 = fmaf(q4.z, kv3[ss].z, a3); a3 = fmaf(q4.w, kv3[ss].w, a3);
                acc[r][0] = a0; acc[r][1] = a1; acc[r][2] = a2; acc[r][3] = a3;
            }
        }
    }

    // flush scaled scores to S (consecutive lanes -> consecutive addresses)
#pragma unroll
    for (int r = 0; r < 8; ++r) {
        S[r][t +    0] = acc[r][0] * 0.125f;
        S[r][t +  512] = acc[r][1] * 0.125f;
        S[r][t + 1024] = acc[r][2] * 0.125f;
        S[r][t + 1536] = acc[r][3] * 0.125f;
    }
    __syncthreads();

    // phase B: ONE row per wave (rr = wid); exact 64th-largest via bisection
    const unsigned long long pre64 = (1ull << lane) - 1ull;
    {
        const int rr = wid;
        float    fv[32];
        unsigned uv[32];
#pragma unroll
        for (int m = 0; m < 32; ++m) {
            const float x = S[rr][lane + (m << 6)];
            fv[m] = x;
            const unsigned bx = __float_as_uint(x);
            uv[m] = bx ^ (unsigned)(((int)bx >> 31) | 0x80000000);
        }
        unsigned lo = 0;
#pragma unroll 1
        for (int bit = 31; bit >= 0; --bit) {
            const unsigned mid = lo | (1u << bit);
            int c = 0;
#pragma unroll
            for (int m = 0; m < 32; ++m)
                c += __popcll(__ballot(uv[m] >= mid));
            if (c >= 64) {
                lo = mid;              // uniform (ballot count is wave-uniform)
                if (c == 64) break;    // kept set is exactly the top-64
            }
        }
        unsigned um = 0;
#pragma unroll
        for (int m = 0; m < 32; ++m) um = uv[m] > um ? uv[m] : um;
#pragma unroll
        for (int off = 1; off < 64; off <<= 1) {
            const unsigned o = (unsigned)__shfl_xor((int)um, off, 64);
            um = o > um ? o : um;
        }
        const unsigned mbm = (um & 0x80000000u) ? (um ^ 0x80000000u) : ~um;
        const float Mx = __uint_as_float(mbm);

        float zs = 0.f;
#pragma unroll
        for (int m = 0; m < 32; ++m) {
            const bool keep = uv[m] >= lo;
            const float ex = keep ? __expf(fv[m] - Mx) : 0.f;
            fv[m] = ex;
            zs += ex;
        }
#pragma unroll
        for (int off = 1; off < 64; off <<= 1) zs += __shfl_xor(zs, off, 64);
        const float zinv = 1.0f / zs;

        const size_t grow = (size_t)bh * 2048 + r0 + rr;
        float* vd           = svals + grow * SLOTS;
        unsigned short* idp = sidx  + grow * SLOTS;
        int base = 0;
#pragma unroll
        for (int m = 0; m < 32; ++m) {
            const bool keep = uv[m] >= lo;
            unsigned long long ball = __ballot(keep);
            if (keep) {
                const int my = base + __popcll(ball & pre64);
                if (my < SLOTS) {
                    vd[my]  = fv[m] * zinv;
                    idp[my] = (unsigned short)(lane + (m << 6));
                }
            }
            base += __popcll(ball);
        }
        if (lane == 0) scnt[grow] = base < SLOTS ? base : SLOTS;
    }
}

// ---------------------------------------------------------------------------
// K3: sparse attn application. Gather loop unrolled x8 (same j order ->
// bit-identical) for more loads in flight.
// ---------------------------------------------------------------------------
__global__ __launch_bounds__(256)
void spmm(const float* __restrict__ svals, const unsigned short* __restrict__ sidx,
          const int* __restrict__ scnt, const float* __restrict__ qkv,
          const float* __restrict__ vin, float* __restrict__ vout,
          float* __restrict__ res, const float* __restrict__ alphas_raw, int order)
{
    const int lane = threadIdx.x & 63;
    const int gr   = (blockIdx.x << 2) + (threadIdx.x >> 6);  // 0..65535
    const int bh   = gr >> 11, n = gr & 2047;
    const int b    = bh >> 3,  h = bh & 7;

    const float* vb;
    int stride;
    if (order == 0) { vb = qkv + (size_t)b * 2048 * 1536 + 1024 + (h << 6); stride = 1536; }
    else            { vb = vin + ((size_t)bh << 17);                        stride = 64;   }

    const int cnt = scnt[gr];
    const float* va          = svals + (size_t)gr * SLOTS;
    const unsigned short* ia = sidx  + (size_t)gr * SLOTS;

    float acc = 0.f;
    int j = 0;
    for (; j + 8 <= cnt; j += 8) {
        float a0 = va[j],     a1 = va[j + 1], a2 = va[j + 2], a3 = va[j + 3];
        float a4 = va[j + 4], a5 = va[j + 5], a6 = va[j + 6], a7 = va[j + 7];
        int   i0 = ia[j],     i1 = ia[j + 1], i2 = ia[j + 2], i3 = ia[j + 3];
        int   i4 = ia[j + 4], i5 = ia[j + 5], i6 = ia[j + 6], i7 = ia[j + 7];
        acc += a0 * vb[(size_t)i0 * stride + lane];
        acc += a1 * vb[(size_t)i1 * stride + lane];
        acc += a2 * vb[(size_t)i2 * stride + lane];
        acc += a3 * vb[(size_t)i3 * stride + lane];
        acc += a4 * vb[(size_t)i4 * stride + lane];
        acc += a5 * vb[(size_t)i5 * stride + lane];
        acc += a6 * vb[(size_t)i6 * stride + lane];
        acc += a7 * vb[(size_t)i7 * stride + lane];
    }
    for (; j < cnt; ++j) acc += va[j] * vb[(size_t)ia[j] * stride + lane];

    if (order < 2) vout[((size_t)gr << 6) + lane] = acc;

    float ar    = alphas_raw[(order << 3) + h];
    float alpha = ar * 0.5f * (1.0f + erff(ar * 0.70710678f));  // exact gelu
    size_t ro = ((size_t)b * 2048 + n) * 512 + (h << 6) + lane;
    float av  = alpha * acc;
    if (order == 0) res[ro] = av;
    else            res[ro] += av;
}

// ---------------------------------------------------------------------------
extern "C" void kernel_launch(void* const* d_in, const int* in_sizes, int n_in,
                              void* d_out, int out_size, void* d_ws, size_t ws_size,
                              hipStream_t stream)
{
    const float* x      = (const float*)d_in[0];
    const float* Wqkv   = (const float*)d_in[1];
    const float* bqkv   = (const float*)d_in[2];
    const float* Wout   = (const float*)d_in[3];
    const float* bout   = (const float*)d_in[4];
    const float* alphas = (const float*)d_in[5];
    float* out = (float*)d_out;

    // workspace layout (bytes)
    char* ws = (char*)d_ws;
    float*          qkvb  = (float*)ws;                       // 8192*1536*4 = 50331648
    float*          svals = (float*)(ws + 50331648);          // 65536*80*4  = 20971520
    unsigned short* sidxp = (unsigned short*)(ws + 71303168); // 65536*80*2  = 10485760
    int*            scntp = (int*)(ws + 81788928);            // 65536*4     = 262144
    float*          v1    = (float*)(ws + 82051072);          // 16777216
    float*          v2    = (float*)(ws + 98828288);          // 16777216
    float*          resb  = (float*)(ws + 115605504);         // 16777216
    if (ws_size < 132382720) return;                          // need ~126 MB

    // K1: qkv = x @ Wqkv + bqkv
    sgemm_bias<<<dim3(1536 / 128, 8192 / 128), 256, 0, stream>>>(
        x, Wqkv, bqkv, qkvb, 8192, 1536, 512);

    // K2: scores -> exact top-64(+ties) -> softmax -> sparse rows
    // 8192 blocks x 512 threads; 8 rows/block; XCD-affine bh mapping
    scores_topk<<<8192, 512, 0, stream>>>(qkvb, svals, sidxp, scntp);

    // K3 x3: polynomial filter (sparse A applications)
    spmm<<<16384, 256, 0, stream>>>(svals, sidxp, scntp, qkvb, nullptr, v1, resb, alphas, 0);
    spmm<<<16384, 256, 0, stream>>>(svals, sidxp, scntp, qkvb, v1, v2, resb, alphas, 1);
    spmm<<<16384, 256, 0, stream>>>(svals, sidxp, scntp, qkvb, v2, nullptr, resb, alphas, 2);

    // K4: out = res @ Wout + bout
    sgemm_bias<<<dim3(512 / 128, 8192 / 128), 256, 0, stream>>>(
        resb, Wout, bout, out, 8192, 512, 512);
}

// Round 13
// 1164.002 us; speedup vs baseline: 1.3474x; 1.1122x over previous
//
#include <hip/hip_runtime.h>
#include <hip/hip_bf16.h>

// Problem constants: B=4, N=2048, DIM=512, H=8, DH=64, ORDER=3, TOPK=64, INNER=512
#define SLOTS 80   // sparse slots per row (64 + tie headroom)

// ---------------------------------------------------------------------------
// K1/K4: fp32 tiled GEMM with bias: C = A(MxK) @ B(KxN) + bias(N)
// BM=BN=128, BK=16, 256 threads, 8x8 per thread. (unchanged)
// ---------------------------------------------------------------------------
__global__ __launch_bounds__(256)
void sgemm_bias(const float* __restrict__ A, const float* __restrict__ Bm,
                const float* __restrict__ bias, float* __restrict__ C,
                int M, int N, int K)
{
    __shared__ float As[16][132];
    __shared__ float Bs[16][132];

    const int t  = threadIdx.x;
    const int tx = t & 15, ty = t >> 4;
    const int bm = blockIdx.y << 7, bn = blockIdx.x << 7;

    const int arow = t >> 2,  ak4 = (t & 3) << 2;
    const int bkr  = t >> 5,  bc4 = (t & 31) << 2;

    float4 pa[2], pb[2];
#pragma unroll
    for (int s = 0; s < 2; ++s) {
        pa[s] = *(const float4*)&A[(size_t)(bm + arow + (s << 6)) * K + ak4];
        pb[s] = *(const float4*)&Bm[(size_t)(bkr + (s << 3)) * N + bn + bc4];
    }

    float acc[8][8] = {};

    for (int k0 = 0; k0 < K; k0 += 16) {
        __syncthreads();
#pragma unroll
        for (int s = 0; s < 2; ++s) {
            const int ar = arow + (s << 6);
            As[ak4 + 0][ar] = pa[s].x;
            As[ak4 + 1][ar] = pa[s].y;
            As[ak4 + 2][ar] = pa[s].z;
            As[ak4 + 3][ar] = pa[s].w;
            *(float4*)&Bs[bkr + (s << 3)][bc4] = pb[s];
        }
        __syncthreads();
        if (k0 + 16 < K) {
#pragma unroll
            for (int s = 0; s < 2; ++s) {
                pa[s] = *(const float4*)&A[(size_t)(bm + arow + (s << 6)) * K + k0 + 16 + ak4];
                pb[s] = *(const float4*)&Bm[(size_t)(k0 + 16 + bkr + (s << 3)) * N + bn + bc4];
            }
        }
#pragma unroll
        for (int kk = 0; kk < 16; ++kk) {
            float4 a0 = *(const float4*)&As[kk][(ty << 3) + 0];
            float4 a1 = *(const float4*)&As[kk][(ty << 3) + 4];
            float4 b0 = *(const float4*)&Bs[kk][(tx << 2)];
            float4 b1 = *(const float4*)&Bs[kk][64 + (tx << 2)];
            float ar[8] = {a0.x, a0.y, a0.z, a0.w, a1.x, a1.y, a1.z, a1.w};
            float br[8] = {b0.x, b0.y, b0.z, b0.w, b1.x, b1.y, b1.z, b1.w};
#pragma unroll
            for (int i = 0; i < 8; ++i)
#pragma unroll
                for (int j = 0; j < 8; ++j)
                    acc[i][j] = fmaf(ar[i], br[j], acc[i][j]);
        }
    }

    float bb[8];
#pragma unroll
    for (int j = 0; j < 4; ++j) {
        bb[j]     = bias[bn + (tx << 2) + j];
        bb[j + 4] = bias[bn + 64 + (tx << 2) + j];
    }
#pragma unroll
    for (int i = 0; i < 8; ++i) {
        const size_t row = (size_t)(bm + (ty << 3) + i);
        float4 o0 = {acc[i][0] + bb[0], acc[i][1] + bb[1], acc[i][2] + bb[2], acc[i][3] + bb[3]};
        float4 o1 = {acc[i][4] + bb[4], acc[i][5] + bb[5], acc[i][6] + bb[6], acc[i][7] + bb[7]};
        *(float4*)&C[row * N + bn + (tx << 2)]      = o0;
        *(float4*)&C[row * N + bn + 64 + (tx << 2)] = o1;
    }
}

// ---------------------------------------------------------------------------
// K2 v13 == R10 EXACTLY (the proven best: 790 us, VALUBusy 45%, clean
// counters). 512 thr / 8 rows / S[8][2048]=64KB / 2 blocks/CU; lane owns 4
// cols; cache-line-linear K reads; natural compiler schedule (no fences —
// R12 measured sched_barrier(0) costs 135 us here); full 32-bit bisection
// (R12's early-exit not isolated as a win). Phase B: 1 row/wave.
// Per-score fmaf chain d-ascending 0..63 -> bit-identical output.
// ---------------------------------------------------------------------------
__global__ __launch_bounds__(512, 4)
void scores_topk(const float* __restrict__ qkv, float* __restrict__ svals,
                 unsigned short* __restrict__ sidx, int* __restrict__ scnt)
{
    __shared__ float S[8][2048];   // 64 KiB

    const int t    = threadIdx.x;
    const int lane = t & 63;
    const int wid  = t >> 6;                        // 0..7
    const int id   = blockIdx.x;                    // 0..8191
    const int bh   = ((id >> 11) << 3) | (id & 7);  // XCD-affine, bijective
    const int rowblk = (id >> 3) & 255;
    const int b = bh >> 3, h = bh & 7;
    const size_t rowbase = (size_t)b * 2048;
    const int r0 = rowblk << 3;                     // block's 8 rows

    // q base for the block's rows (uniform across lanes -> scalar loads)
    const float* qb = qkv + (rowbase + r0) * 1536 + (h << 6);
    // lane's 4 K-columns: t + {0, 512, 1024, 1536}
    const float* k0 = qkv + (rowbase + (size_t)t) * 1536 + 512 + (h << 6);

    float acc[8][4];
#pragma unroll
    for (int r = 0; r < 8; ++r)
#pragma unroll
        for (int c = 0; c < 4; ++c) acc[r][c] = 0.f;

#pragma unroll 1
    for (int sg = 0; sg < 4; ++sg) {
        // load each column's full 64B chunk (4 consecutive float4: same line)
        float4 kv0[4], kv1[4], kv2[4], kv3[4];
#pragma unroll
        for (int j = 0; j < 4; ++j) {
            kv0[j] = *(const float4*)&k0[                   (sg << 4) + (j << 2)];
            kv1[j] = *(const float4*)&k0[ 512 * 1536 +      (sg << 4) + (j << 2)];
            kv2[j] = *(const float4*)&k0[1024 * 1536 +      (sg << 4) + (j << 2)];
            kv3[j] = *(const float4*)&k0[1536 * 1536 +      (sg << 4) + (j << 2)];
        }
#pragma unroll
        for (int ss = 0; ss < 4; ++ss) {
#pragma unroll
            for (int r = 0; r < 8; ++r) {
                const float4 q4 = *(const float4*)&qb[r * 1536 + (sg << 4) + (ss << 2)];
                float a0 = acc[r][0], a1 = acc[r][1], a2 = acc[r][2], a3 = acc[r][3];
                a0 = fmaf(q4.x, kv0[ss].x, a0); a0 = fmaf(q4.y, kv0[ss].y, a0);
                a0 = fmaf(q4.z, kv0[ss].z, a0); a0 = fmaf(q4.w, kv0[ss].w, a0);
                a1 = fmaf(q4.x, kv1[ss].x, a1); a1 = fmaf(q4.y, kv1[ss].y, a1);
                a1 = fmaf(q4.z, kv1[ss].z, a1); a1 = fmaf(q4.w, kv1[ss].w, a1);
                a2 = fmaf(q4.x, kv2[ss].x, a2); a2 = fmaf(q4.y, kv2[ss].y, a2);
                a2 = fmaf(q4.z, kv2[ss].z, a2); a2 = fmaf(q4.w, kv2[ss].w, a2);
                a3 = fmaf(q4.x, kv3[ss].x, a3); a3 = fmaf(q4.y, kv3[ss].y, a3);
                a3 = fmaf(q4.z, kv3[ss].z, a3); a3 = fmaf(q4.w, kv3[ss].w, a3);
                acc[r][0] = a0; acc[r][1] = a1; acc[r][2] = a2; acc[r][3] = a3;
            }
        }
    }

    // flush scaled scores to S (consecutive lanes -> consecutive addresses)
#pragma unroll
    for (int r = 0; r < 8; ++r) {
        S[r][t +    0] = acc[r][0] * 0.125f;
        S[r][t +  512] = acc[r][1] * 0.125f;
        S[r][t + 1024] = acc[r][2] * 0.125f;
        S[r][t + 1536] = acc[r][3] * 0.125f;
    }
    __syncthreads();

    // phase B: ONE row per wave (rr = wid); exact 64th-largest via bisection
    const unsigned long long pre64 = (1ull << lane) - 1ull;
    {
        const int rr = wid;
        float    fv[32];
        unsigned uv[32];
#pragma unroll
        for (int m = 0; m < 32; ++m) {
            const float x = S[rr][lane + (m << 6)];
            fv[m] = x;
            const unsigned bx = __float_as_uint(x);
            uv[m] = bx ^ (unsigned)(((int)bx >> 31) | 0x80000000);
        }
        unsigned lo = 0;
#pragma unroll 1
        for (int bit = 31; bit >= 0; --bit) {
            const unsigned mid = lo | (1u << bit);
            int c = 0;
#pragma unroll
            for (int m = 0; m < 32; ++m)
                c += __popcll(__ballot(uv[m] >= mid));
            if (c >= 64) lo = mid;   // uniform (ballot count is wave-uniform)
        }
        unsigned um = 0;
#pragma unroll
        for (int m = 0; m < 32; ++m) um = uv[m] > um ? uv[m] : um;
#pragma unroll
        for (int off = 1; off < 64; off <<= 1) {
            const unsigned o = (unsigned)__shfl_xor((int)um, off, 64);
            um = o > um ? o : um;
        }
        const unsigned mbm = (um & 0x80000000u) ? (um ^ 0x80000000u) : ~um;
        const float Mx = __uint_as_float(mbm);

        float zs = 0.f;
#pragma unroll
        for (int m = 0; m < 32; ++m) {
            const bool keep = uv[m] >= lo;
            const float ex = keep ? __expf(fv[m] - Mx) : 0.f;
            fv[m] = ex;
            zs += ex;
        }
#pragma unroll
        for (int off = 1; off < 64; off <<= 1) zs += __shfl_xor(zs, off, 64);
        const float zinv = 1.0f / zs;

        const size_t grow = (size_t)bh * 2048 + r0 + rr;
        float* vd           = svals + grow * SLOTS;
        unsigned short* idp = sidx  + grow * SLOTS;
        int base = 0;
#pragma unroll
        for (int m = 0; m < 32; ++m) {
            const bool keep = uv[m] >= lo;
            unsigned long long ball = __ballot(keep);
            if (keep) {
                const int my = base + __popcll(ball & pre64);
                if (my < SLOTS) {
                    vd[my]  = fv[m] * zinv;
                    idp[my] = (unsigned short)(lane + (m << 6));
                }
            }
            base += __popcll(ball);
        }
        if (lane == 0) scnt[grow] = base < SLOTS ? base : SLOTS;
    }
}

// ---------------------------------------------------------------------------
// K3: sparse attn application. Gather loop unrolled x8 (measured ~90-100 us
// total win vs x4 across the 3 dispatches; same j order -> bit-identical).
// ---------------------------------------------------------------------------
__global__ __launch_bounds__(256)
void spmm(const float* __restrict__ svals, const unsigned short* __restrict__ sidx,
          const int* __restrict__ scnt, const float* __restrict__ qkv,
          const float* __restrict__ vin, float* __restrict__ vout,
          float* __restrict__ res, const float* __restrict__ alphas_raw, int order)
{
    const int lane = threadIdx.x & 63;
    const int gr   = (blockIdx.x << 2) + (threadIdx.x >> 6);  // 0..65535
    const int bh   = gr >> 11, n = gr & 2047;
    const int b    = bh >> 3,  h = bh & 7;

    const float* vb;
    int stride;
    if (order == 0) { vb = qkv + (size_t)b * 2048 * 1536 + 1024 + (h << 6); stride = 1536; }
    else            { vb = vin + ((size_t)bh << 17);                        stride = 64;   }

    const int cnt = scnt[gr];
    const float* va          = svals + (size_t)gr * SLOTS;
    const unsigned short* ia = sidx  + (size_t)gr * SLOTS;

    float acc = 0.f;
    int j = 0;
    for (; j + 8 <= cnt; j += 8) {
        float a0 = va[j],     a1 = va[j + 1], a2 = va[j + 2], a3 = va[j + 3];
        float a4 = va[j + 4], a5 = va[j + 5], a6 = va[j + 6], a7 = va[j + 7];
        int   i0 = ia[j],     i1 = ia[j + 1], i2 = ia[j + 2], i3 = ia[j + 3];
        int   i4 = ia[j + 4], i5 = ia[j + 5], i6 = ia[j + 6], i7 = ia[j + 7];
        acc += a0 * vb[(size_t)i0 * stride + lane];
        acc += a1 * vb[(size_t)i1 * stride + lane];
        acc += a2 * vb[(size_t)i2 * stride + lane];
        acc += a3 * vb[(size_t)i3 * stride + lane];
        acc += a4 * vb[(size_t)i4 * stride + lane];
        acc += a5 * vb[(size_t)i5 * stride + lane];
        acc += a6 * vb[(size_t)i6 * stride + lane];
        acc += a7 * vb[(size_t)i7 * stride + lane];
    }
    for (; j < cnt; ++j) acc += va[j] * vb[(size_t)ia[j] * stride + lane];

    if (order < 2) vout[((size_t)gr << 6) + lane] = acc;

    float ar    = alphas_raw[(order << 3) + h];
    float alpha = ar * 0.5f * (1.0f + erff(ar * 0.70710678f));  // exact gelu
    size_t ro = ((size_t)b * 2048 + n) * 512 + (h << 6) + lane;
    float av  = alpha * acc;
    if (order == 0) res[ro] = av;
    else            res[ro] += av;
}

// ---------------------------------------------------------------------------
extern "C" void kernel_launch(void* const* d_in, const int* in_sizes, int n_in,
                              void* d_out, int out_size, void* d_ws, size_t ws_size,
                              hipStream_t stream)
{
    const float* x      = (const float*)d_in[0];
    const float* Wqkv   = (const float*)d_in[1];
    const float* bqkv   = (const float*)d_in[2];
    const float* Wout   = (const float*)d_in[3];
    const float* bout   = (const float*)d_in[4];
    const float* alphas = (const float*)d_in[5];
    float* out = (float*)d_out;

    // workspace layout (bytes)
    char* ws = (char*)d_ws;
    float*          qkvb  = (float*)ws;                       // 8192*1536*4 = 50331648
    float*          svals = (float*)(ws + 50331648);          // 65536*80*4  = 20971520
    unsigned short* sidxp = (unsigned short*)(ws + 71303168); // 65536*80*2  = 10485760
    int*            scntp = (int*)(ws + 81788928);            // 65536*4     = 262144
    float*          v1    = (float*)(ws + 82051072);          // 16777216
    float*          v2    = (float*)(ws + 98828288);          // 16777216
    float*          resb  = (float*)(ws + 115605504);         // 16777216
    if (ws_size < 132382720) return;                          // need ~126 MB

    // K1: qkv = x @ Wqkv + bqkv
    sgemm_bias<<<dim3(1536 / 128, 8192 / 128), 256, 0, stream>>>(
        x, Wqkv, bqkv, qkvb, 8192, 1536, 512);

    // K2: scores -> exact top-64(+ties) -> softmax -> sparse rows
    // 8192 blocks x 512 threads; 8 rows/block; XCD-affine bh mapping
    scores_topk<<<8192, 512, 0, stream>>>(qkvb, svals, sidxp, scntp);

    // K3 x3: polynomial filter (sparse A applications)
    spmm<<<16384, 256, 0, stream>>>(svals, sidxp, scntp, qkvb, nullptr, v1, resb, alphas, 0);
    spmm<<<16384, 256, 0, stream>>>(svals, sidxp, scntp, qkvb, v1, v2, resb, alphas, 1);
    spmm<<<16384, 256, 0, stream>>>(svals, sidxp, scntp, qkvb, v2, nullptr, resb, alphas, 2);

    // K4: out = res @ Wout + bout
    sgemm_bias<<<dim3(512 / 128, 8192 / 128), 256, 0, stream>>>(
        resb, Wout, bout, out, 8192, 512, 512);
}

// Round 14
// 1125.079 us; speedup vs baseline: 1.3940x; 1.0346x over previous
//
#include <hip/hip_runtime.h>
#include <hip/hip_bf16.h>

// Problem constants: B=4, N=2048, DIM=512, H=8, DH=64, ORDER=3, TOPK=64, INNER=512
#define SLOTS 80   // sparse slots per row (64 + tie headroom)

// ---------------------------------------------------------------------------
// K1/K4: fp32 tiled GEMM with bias: C = A(MxK) @ B(KxN) + bias(N)
// BM=BN=128, BK=16, 256 threads, 8x8 per thread. (unchanged)
// ---------------------------------------------------------------------------
__global__ __launch_bounds__(256)
void sgemm_bias(const float* __restrict__ A, const float* __restrict__ Bm,
                const float* __restrict__ bias, float* __restrict__ C,
                int M, int N, int K)
{
    __shared__ float As[16][132];
    __shared__ float Bs[16][132];

    const int t  = threadIdx.x;
    const int tx = t & 15, ty = t >> 4;
    const int bm = blockIdx.y << 7, bn = blockIdx.x << 7;

    const int arow = t >> 2,  ak4 = (t & 3) << 2;
    const int bkr  = t >> 5,  bc4 = (t & 31) << 2;

    float4 pa[2], pb[2];
#pragma unroll
    for (int s = 0; s < 2; ++s) {
        pa[s] = *(const float4*)&A[(size_t)(bm + arow + (s << 6)) * K + ak4];
        pb[s] = *(const float4*)&Bm[(size_t)(bkr + (s << 3)) * N + bn + bc4];
    }

    float acc[8][8] = {};

    for (int k0 = 0; k0 < K; k0 += 16) {
        __syncthreads();
#pragma unroll
        for (int s = 0; s < 2; ++s) {
            const int ar = arow + (s << 6);
            As[ak4 + 0][ar] = pa[s].x;
            As[ak4 + 1][ar] = pa[s].y;
            As[ak4 + 2][ar] = pa[s].z;
            As[ak4 + 3][ar] = pa[s].w;
            *(float4*)&Bs[bkr + (s << 3)][bc4] = pb[s];
        }
        __syncthreads();
        if (k0 + 16 < K) {
#pragma unroll
            for (int s = 0; s < 2; ++s) {
                pa[s] = *(const float4*)&A[(size_t)(bm + arow + (s << 6)) * K + k0 + 16 + ak4];
                pb[s] = *(const float4*)&Bm[(size_t)(k0 + 16 + bkr + (s << 3)) * N + bn + bc4];
            }
        }
#pragma unroll
        for (int kk = 0; kk < 16; ++kk) {
            float4 a0 = *(const float4*)&As[kk][(ty << 3) + 0];
            float4 a1 = *(const float4*)&As[kk][(ty << 3) + 4];
            float4 b0 = *(const float4*)&Bs[kk][(tx << 2)];
            float4 b1 = *(const float4*)&Bs[kk][64 + (tx << 2)];
            float ar[8] = {a0.x, a0.y, a0.z, a0.w, a1.x, a1.y, a1.z, a1.w};
            float br[8] = {b0.x, b0.y, b0.z, b0.w, b1.x, b1.y, b1.z, b1.w};
#pragma unroll
            for (int i = 0; i < 8; ++i)
#pragma unroll
                for (int j = 0; j < 8; ++j)
                    acc[i][j] = fmaf(ar[i], br[j], acc[i][j]);
        }
    }

    float bb[8];
#pragma unroll
    for (int j = 0; j < 4; ++j) {
        bb[j]     = bias[bn + (tx << 2) + j];
        bb[j + 4] = bias[bn + 64 + (tx << 2) + j];
    }
#pragma unroll
    for (int i = 0; i < 8; ++i) {
        const size_t row = (size_t)(bm + (ty << 3) + i);
        float4 o0 = {acc[i][0] + bb[0], acc[i][1] + bb[1], acc[i][2] + bb[2], acc[i][3] + bb[3]};
        float4 o1 = {acc[i][4] + bb[4], acc[i][5] + bb[5], acc[i][6] + bb[6], acc[i][7] + bb[7]};
        *(float4*)&C[row * N + bn + (tx << 2)]      = o0;
        *(float4*)&C[row * N + bn + 64 + (tx << 2)] = o1;
    }
}

// ---------------------------------------------------------------------------
// K2 v14 = R10/R13 structure EXACTLY, plus ONE isolated delta: early-exit
// bisection (break when count(>=mid)==64; the kept set is then provably
// identical to the full-bisection kept set -> bit-identical output).
// No fences (R12 measured sched_barrier(0) = -135 us here).
// ---------------------------------------------------------------------------
__global__ __launch_bounds__(512, 4)
void scores_topk(const float* __restrict__ qkv, float* __restrict__ svals,
                 unsigned short* __restrict__ sidx, int* __restrict__ scnt)
{
    __shared__ float S[8][2048];   // 64 KiB

    const int t    = threadIdx.x;
    const int lane = t & 63;
    const int wid  = t >> 6;                        // 0..7
    const int id   = blockIdx.x;                    // 0..8191
    const int bh   = ((id >> 11) << 3) | (id & 7);  // XCD-affine, bijective
    const int rowblk = (id >> 3) & 255;
    const int b = bh >> 3, h = bh & 7;
    const size_t rowbase = (size_t)b * 2048;
    const int r0 = rowblk << 3;                     // block's 8 rows

    // q base for the block's rows (uniform across lanes -> scalar loads)
    const float* qb = qkv + (rowbase + r0) * 1536 + (h << 6);
    // lane's 4 K-columns: t + {0, 512, 1024, 1536}
    const float* k0 = qkv + (rowbase + (size_t)t) * 1536 + 512 + (h << 6);

    float acc[8][4];
#pragma unroll
    for (int r = 0; r < 8; ++r)
#pragma unroll
        for (int c = 0; c < 4; ++c) acc[r][c] = 0.f;

#pragma unroll 1
    for (int sg = 0; sg < 4; ++sg) {
        // load each column's full 64B chunk (4 consecutive float4: same line)
        float4 kv0[4], kv1[4], kv2[4], kv3[4];
#pragma unroll
        for (int j = 0; j < 4; ++j) {
            kv0[j] = *(const float4*)&k0[                   (sg << 4) + (j << 2)];
            kv1[j] = *(const float4*)&k0[ 512 * 1536 +      (sg << 4) + (j << 2)];
            kv2[j] = *(const float4*)&k0[1024 * 1536 +      (sg << 4) + (j << 2)];
            kv3[j] = *(const float4*)&k0[1536 * 1536 +      (sg << 4) + (j << 2)];
        }
#pragma unroll
        for (int ss = 0; ss < 4; ++ss) {
#pragma unroll
            for (int r = 0; r < 8; ++r) {
                const float4 q4 = *(const float4*)&qb[r * 1536 + (sg << 4) + (ss << 2)];
                float a0 = acc[r][0], a1 = acc[r][1], a2 = acc[r][2], a3 = acc[r][3];
                a0 = fmaf(q4.x, kv0[ss].x, a0); a0 = fmaf(q4.y, kv0[ss].y, a0);
                a0 = fmaf(q4.z, kv0[ss].z, a0); a0 = fmaf(q4.w, kv0[ss].w, a0);
                a1 = fmaf(q4.x, kv1[ss].x, a1); a1 = fmaf(q4.y, kv1[ss].y, a1);
                a1 = fmaf(q4.z, kv1[ss].z, a1); a1 = fmaf(q4.w, kv1[ss].w, a1);
                a2 = fmaf(q4.x, kv2[ss].x, a2); a2 = fmaf(q4.y, kv2[ss].y, a2);
                a2 = fmaf(q4.z, kv2[ss].z, a2); a2 = fmaf(q4.w, kv2[ss].w, a2);
                a3 = fmaf(q4.x, kv3[ss].x, a3); a3 = fmaf(q4.y, kv3[ss].y, a3);
                a3 = fmaf(q4.z, kv3[ss].z, a3); a3 = fmaf(q4.w, kv3[ss].w, a3);
                acc[r][0] = a0; acc[r][1] = a1; acc[r][2] = a2; acc[r][3] = a3;
            }
        }
    }

    // flush scaled scores to S (consecutive lanes -> consecutive addresses)
#pragma unroll
    for (int r = 0; r < 8; ++r) {
        S[r][t +    0] = acc[r][0] * 0.125f;
        S[r][t +  512] = acc[r][1] * 0.125f;
        S[r][t + 1024] = acc[r][2] * 0.125f;
        S[r][t + 1536] = acc[r][3] * 0.125f;
    }
    __syncthreads();

    // phase B: ONE row per wave (rr = wid); exact 64th-largest via bisection
    const unsigned long long pre64 = (1ull << lane) - 1ull;
    {
        const int rr = wid;
        float    fv[32];
        unsigned uv[32];
#pragma unroll
        for (int m = 0; m < 32; ++m) {
            const float x = S[rr][lane + (m << 6)];
            fv[m] = x;
            const unsigned bx = __float_as_uint(x);
            uv[m] = bx ^ (unsigned)(((int)bx >> 31) | 0x80000000);
        }
        unsigned lo = 0;
#pragma unroll 1
        for (int bit = 31; bit >= 0; --bit) {
            const unsigned mid = lo | (1u << bit);
            int c = 0;
#pragma unroll
            for (int m = 0; m < 32; ++m)
                c += __popcll(__ballot(uv[m] >= mid));
            if (c >= 64) {
                lo = mid;              // uniform (ballot count is wave-uniform)
                if (c == 64) break;    // kept set already exact: {uv>=lo} is
                                       // provably == full-bisection kept set
            }
        }
        unsigned um = 0;
#pragma unroll
        for (int m = 0; m < 32; ++m) um = uv[m] > um ? uv[m] : um;
#pragma unroll
        for (int off = 1; off < 64; off <<= 1) {
            const unsigned o = (unsigned)__shfl_xor((int)um, off, 64);
            um = o > um ? o : um;
        }
        const unsigned mbm = (um & 0x80000000u) ? (um ^ 0x80000000u) : ~um;
        const float Mx = __uint_as_float(mbm);

        float zs = 0.f;
#pragma unroll
        for (int m = 0; m < 32; ++m) {
            const bool keep = uv[m] >= lo;
            const float ex = keep ? __expf(fv[m] - Mx) : 0.f;
            fv[m] = ex;
            zs += ex;
        }
#pragma unroll
        for (int off = 1; off < 64; off <<= 1) zs += __shfl_xor(zs, off, 64);
        const float zinv = 1.0f / zs;

        const size_t grow = (size_t)bh * 2048 + r0 + rr;
        float* vd           = svals + grow * SLOTS;
        unsigned short* idp = sidx  + grow * SLOTS;
        int base = 0;
#pragma unroll
        for (int m = 0; m < 32; ++m) {
            const bool keep = uv[m] >= lo;
            unsigned long long ball = __ballot(keep);
            if (keep) {
                const int my = base + __popcll(ball & pre64);
                if (my < SLOTS) {
                    vd[my]  = fv[m] * zinv;
                    idp[my] = (unsigned short)(lane + (m << 6));
                }
            }
            base += __popcll(ball);
        }
        if (lane == 0) scnt[grow] = base < SLOTS ? base : SLOTS;
    }
}

// ---------------------------------------------------------------------------
// K3: sparse attn application, x8 unroll (kept from R13), plus XCD-AFFINE
// block mapping: same-bh blocks land on the same XCD (id mod 8 constant per
// bh) so each 512KB V panel is pulled into ONE XCD's L2 instead of all 8.
// Mapping is bijective; per-row arithmetic unchanged -> bit-identical.
// ---------------------------------------------------------------------------
__global__ __launch_bounds__(256)
void spmm(const float* __restrict__ svals, const unsigned short* __restrict__ sidx,
          const int* __restrict__ scnt, const float* __restrict__ qkv,
          const float* __restrict__ vin, float* __restrict__ vout,
          float* __restrict__ res, const float* __restrict__ alphas_raw, int order)
{
    const int lane = threadIdx.x & 63;
    const int id   = blockIdx.x;                      // 0..16383
    const int bh   = ((id & 7) << 2) | (id >> 12);    // XCD-affine, bijective
    const int nblk = (id >> 3) & 511;
    const int n    = (nblk << 2) + (threadIdx.x >> 6);
    const int gr   = (bh << 11) + n;
    const int b    = bh >> 3,  h = bh & 7;

    const float* vb;
    int stride;
    if (order == 0) { vb = qkv + (size_t)b * 2048 * 1536 + 1024 + (h << 6); stride = 1536; }
    else            { vb = vin + ((size_t)bh << 17);                        stride = 64;   }

    const int cnt = scnt[gr];
    const float* va          = svals + (size_t)gr * SLOTS;
    const unsigned short* ia = sidx  + (size_t)gr * SLOTS;

    float acc = 0.f;
    int j = 0;
    for (; j + 8 <= cnt; j += 8) {
        float a0 = va[j],     a1 = va[j + 1], a2 = va[j + 2], a3 = va[j + 3];
        float a4 = va[j + 4], a5 = va[j + 5], a6 = va[j + 6], a7 = va[j + 7];
        int   i0 = ia[j],     i1 = ia[j + 1], i2 = ia[j + 2], i3 = ia[j + 3];
        int   i4 = ia[j + 4], i5 = ia[j + 5], i6 = ia[j + 6], i7 = ia[j + 7];
        acc += a0 * vb[(size_t)i0 * stride + lane];
        acc += a1 * vb[(size_t)i1 * stride + lane];
        acc += a2 * vb[(size_t)i2 * stride + lane];
        acc += a3 * vb[(size_t)i3 * stride + lane];
        acc += a4 * vb[(size_t)i4 * stride + lane];
        acc += a5 * vb[(size_t)i5 * stride + lane];
        acc += a6 * vb[(size_t)i6 * stride + lane];
        acc += a7 * vb[(size_t)i7 * stride + lane];
    }
    for (; j < cnt; ++j) acc += va[j] * vb[(size_t)ia[j] * stride + lane];

    if (order < 2) vout[((size_t)gr << 6) + lane] = acc;

    float ar    = alphas_raw[(order << 3) + h];
    float alpha = ar * 0.5f * (1.0f + erff(ar * 0.70710678f));  // exact gelu
    size_t ro = ((size_t)b * 2048 + n) * 512 + (h << 6) + lane;
    float av  = alpha * acc;
    if (order == 0) res[ro] = av;
    else            res[ro] += av;
}

// ---------------------------------------------------------------------------
extern "C" void kernel_launch(void* const* d_in, const int* in_sizes, int n_in,
                              void* d_out, int out_size, void* d_ws, size_t ws_size,
                              hipStream_t stream)
{
    const float* x      = (const float*)d_in[0];
    const float* Wqkv   = (const float*)d_in[1];
    const float* bqkv   = (const float*)d_in[2];
    const float* Wout   = (const float*)d_in[3];
    const float* bout   = (const float*)d_in[4];
    const float* alphas = (const float*)d_in[5];
    float* out = (float*)d_out;

    // workspace layout (bytes)
    char* ws = (char*)d_ws;
    float*          qkvb  = (float*)ws;                       // 8192*1536*4 = 50331648
    float*          svals = (float*)(ws + 50331648);          // 65536*80*4  = 20971520
    unsigned short* sidxp = (unsigned short*)(ws + 71303168); // 65536*80*2  = 10485760
    int*            scntp = (int*)(ws + 81788928);            // 65536*4     = 262144
    float*          v1    = (float*)(ws + 82051072);          // 16777216
    float*          v2    = (float*)(ws + 98828288);          // 16777216
    float*          resb  = (float*)(ws + 115605504);         // 16777216
    if (ws_size < 132382720) return;                          // need ~126 MB

    // K1: qkv = x @ Wqkv + bqkv
    sgemm_bias<<<dim3(1536 / 128, 8192 / 128), 256, 0, stream>>>(
        x, Wqkv, bqkv, qkvb, 8192, 1536, 512);

    // K2: scores -> exact top-64(+ties) -> softmax -> sparse rows
    scores_topk<<<8192, 512, 0, stream>>>(qkvb, svals, sidxp, scntp);

    // K3 x3: polynomial filter (sparse A applications)
    spmm<<<16384, 256, 0, stream>>>(svals, sidxp, scntp, qkvb, nullptr, v1, resb, alphas, 0);
    spmm<<<16384, 256, 0, stream>>>(svals, sidxp, scntp, qkvb, v1, v2, resb, alphas, 1);
    spmm<<<16384, 256, 0, stream>>>(svals, sidxp, scntp, qkvb, v2, nullptr, resb, alphas, 2);

    // K4: out = res @ Wout + bout
    sgemm_bias<<<dim3(512 / 128, 8192 / 128), 256, 0, stream>>>(
        resb, Wout, bout, out, 8192, 512, 512);
}